// Round 3
// baseline (526.197 us; speedup 1.0000x reference)
//
#include <hip/hip_runtime.h>

// GraphAttention: e[b,n,k,o] = T[b,n,o] + U[b,idx[b,n,k],o]  (exact factorization
// of einsum('bnkc,oc', [centre-nb, nb], W)); BN affine folded into T,U.
// Then leaky(0.2) -> softmax over k -> dot with feature[b,o,n,:] -> out[b,o,n].
//
// R1 change (unbenched due to GPU timeout, resubmitted verbatim): non-temporal
// loads on all read-once streams (feature/gi/T/x) and NT stores on out, so the
// 256MB feature stream stops thrashing U[b] (1MB, XCD-pinned) out of L2;
// unroll 2 rows for gather ILP.

constexpr int B_ = 8, C_ = 64, N_ = 4096, K_ = 32, O_ = 64;
typedef float v4 __attribute__((ext_vector_type(4)));

// ---------------- Kernel A: T'[b,n,o], U'[b,n,o] precompute ----------------
__global__ __launch_bounds__(256) void gat_pre(
    const float* __restrict__ x, const float* __restrict__ W,
    const float* __restrict__ gamma, const float* __restrict__ beta,
    const float* __restrict__ bn_mean, const float* __restrict__ bn_var,
    float* __restrict__ T, float* __restrict__ U)
{
    __shared__ float xsT[64][68];   // [c][n_local]
    __shared__ float wt1[64][68];   // [c][o] = W1[o][c]
    __shared__ float wtd[64][68];   // [c][o] = W2[o][c]-W1[o][c]

    const int blk = blockIdx.x;
    const int b = blk & 7;                 // XCD-pinned batch
    const int n_base = (blk >> 3) << 6;
    const int t = threadIdx.x;

    const float* xb = x + ((size_t)b * N_ + n_base) * C_;
    #pragma unroll
    for (int r = 0; r < 4; ++r) {
        const int e0 = r * 1024 + t * 4;
        const v4 v = __builtin_nontemporal_load(reinterpret_cast<const v4*>(xb + e0));
        xsT[(e0 + 0) & 63][(e0 + 0) >> 6] = v.x;
        xsT[(e0 + 1) & 63][(e0 + 1) >> 6] = v.y;
        xsT[(e0 + 2) & 63][(e0 + 2) >> 6] = v.z;
        xsT[(e0 + 3) & 63][(e0 + 3) >> 6] = v.w;
    }
    #pragma unroll
    for (int i = 0; i < 16; ++i) {
        const int idx = i * 256 + t;
        const int o = idx >> 6, c = idx & 63;
        const float w1 = W[o * 128 + c];
        const float w2 = W[o * 128 + 64 + c];
        wt1[c][o] = w1;
        wtd[c][o] = w2 - w1;
    }
    __syncthreads();

    const int o0 = (t & 15) * 4;
    const int n0 = (t >> 4) * 4;
    float accT[4][4] = {};
    float accU[4][4] = {};
    #pragma unroll 4
    for (int c = 0; c < 64; ++c) {
        const v4 xn = *reinterpret_cast<const v4*>(&xsT[c][n0]);
        const v4 w1 = *reinterpret_cast<const v4*>(&wt1[c][o0]);
        const v4 wd = *reinterpret_cast<const v4*>(&wtd[c][o0]);
        const float xa[4] = {xn.x, xn.y, xn.z, xn.w};
        const float wa[4] = {w1.x, w1.y, w1.z, w1.w};
        const float da[4] = {wd.x, wd.y, wd.z, wd.w};
        #pragma unroll
        for (int i = 0; i < 4; ++i)
            #pragma unroll
            for (int j = 0; j < 4; ++j) {
                accT[i][j] = fmaf(xa[i], wa[j], accT[i][j]);
                accU[i][j] = fmaf(xa[i], da[j], accU[i][j]);
            }
    }

    float inv[4], bias[4];
    #pragma unroll
    for (int j = 0; j < 4; ++j) {
        const int o = o0 + j;
        const float iv = gamma[o] * rsqrtf(bn_var[o] + 1e-5f);
        inv[j] = iv;
        bias[j] = beta[o] - bn_mean[o] * iv;
    }
    #pragma unroll
    for (int i = 0; i < 4; ++i) {
        const int n = n_base + n0 + i;
        float tvv[4], uvv[4];
        #pragma unroll
        for (int j = 0; j < 4; ++j) {
            tvv[j] = fmaf(accT[i][j], inv[j], bias[j]);
            uvv[j] = accU[i][j] * inv[j];
        }
        // normal (cached) stores: T/U are consumed by gat_main on the same XCD
        float* tp = T + ((size_t)b * N_ + n) * O_ + o0;
        float* up = U + ((size_t)b * N_ + n) * O_ + o0;
        *reinterpret_cast<v4*>(tp) = (v4){tvv[0], tvv[1], tvv[2], tvv[3]};
        *reinterpret_cast<v4*>(up) = (v4){uvv[0], uvv[1], uvv[2], uvv[3]};
    }
}

// ---------------- Kernel B: gather + softmax + weighted feature sum ----------------
__global__ __launch_bounds__(256) void gat_main(
    const int* __restrict__ gi, const float* __restrict__ feat,
    const float* __restrict__ T, const float* __restrict__ U,
    float* __restrict__ out)
{
    __shared__ float tmp[64][17];
    const int blk = blockIdx.x;
    const int b = blk & 7;                 // XCD-pinned batch
    const int n_base = (blk >> 3) * 16;
    const int t = threadIdx.x;
    const int w = t >> 6;
    const int lane = t & 63;               // = o

    const float* Ub = U + (size_t)b * N_ * O_ + lane;   // L2-resident gathers

    #pragma unroll 2
    for (int r = 0; r < 4; ++r) {
        const int n = n_base + w * 4 + r;
        int vi = 0;
        if (lane < 32) vi = __builtin_nontemporal_load(&gi[((size_t)b * N_ + n) * K_ + lane]);
        const float tv = __builtin_nontemporal_load(&T[((size_t)b * N_ + n) * O_ + lane]);

        float e[32];
        float emax = -3.0e38f;
        #pragma unroll
        for (int k = 0; k < 32; ++k) {
            const int m = __shfl(vi, k, 64);
            const float u = Ub[m * O_];    // normal load: keep U in L2
            float ev = tv + u;
            ev = fmaxf(ev, 0.2f * ev);     // leaky relu, slope 0.2
            e[k] = ev;
            emax = fmaxf(emax, ev);
        }

        const v4* fp = reinterpret_cast<const v4*>(feat + (((size_t)b * O_ + lane) * N_ + n) * K_);
        float num = 0.f, den = 0.f;
        #pragma unroll
        for (int k4 = 0; k4 < 8; ++k4) {
            const v4 f = __builtin_nontemporal_load(fp + k4);   // read-once stream
            const float p0 = __expf(e[k4 * 4 + 0] - emax);
            const float p1 = __expf(e[k4 * 4 + 1] - emax);
            const float p2 = __expf(e[k4 * 4 + 2] - emax);
            const float p3 = __expf(e[k4 * 4 + 3] - emax);
            num = fmaf(p0, f.x, num); den += p0;
            num = fmaf(p1, f.y, num); den += p1;
            num = fmaf(p2, f.z, num); den += p2;
            num = fmaf(p3, f.w, num); den += p3;
        }
        tmp[lane][w * 4 + r] = num / den;
    }
    __syncthreads();

    // coalesced transpose-write: 16 consecutive n per o = one 64B line
    #pragma unroll
    for (int r = 0; r < 4; ++r) {
        const int o = r * 16 + (t >> 4);
        const int ns = t & 15;
        __builtin_nontemporal_store(tmp[o][ns],
            &out[((size_t)b * O_ + o) * N_ + n_base + ns]);
    }
}

extern "C" void kernel_launch(void* const* d_in, const int* in_sizes, int n_in,
                              void* d_out, int out_size, void* d_ws, size_t ws_size,
                              hipStream_t stream) {
    const int*   gi      = (const int*)d_in[0];
    const float* x       = (const float*)d_in[1];
    const float* feat    = (const float*)d_in[2];
    const float* W       = (const float*)d_in[3];
    const float* gamma   = (const float*)d_in[4];
    const float* beta    = (const float*)d_in[5];
    const float* bn_mean = (const float*)d_in[6];
    const float* bn_var  = (const float*)d_in[7];
    float* out = (float*)d_out;

    float* T = (float*)d_ws;                          // B*N*O floats = 8MB
    float* U = T + (size_t)B_ * N_ * O_;              // + 8MB

    gat_pre<<<dim3(B_ * (N_ / 64)), dim3(256), 0, stream>>>(
        x, W, gamma, beta, bn_mean, bn_var, T, U);
    gat_main<<<dim3(B_ * (N_ / 16)), dim3(256), 0, stream>>>(
        gi, feat, T, U, out);
}

// Round 10
// 425.534 us; speedup vs baseline: 1.2366x; 1.2366x over previous
//
#include <hip/hip_runtime.h>

// GraphAttention: e[b,n,k,o] = T[b,n,o] + U[b,idx[b,n,k],o]  (exact factorization
// of einsum('bnkc,oc', [centre-nb, nb], W)); BN affine folded into T,U.
// Then leaky(0.2) -> softmax over k -> dot with feature[b,o,n,:] -> out[b,o,n].
//
// R3 (resubmitted after 6th GPU timeout; unmeasured): NT on feat re-fetched
// each 128B line up to 8x (FETCH 434MB vs 280MB compulsory, dur 212us). Revert
// feat to cached loads. NT stays only on true single-use data (gi/T/x) + out
// stores. Issue all 40 independent loads (8 feat dwordx4 + 32 U gathers)
// BEFORE any consumption -> 40-deep MLP per wave for the latency-bound phase.

constexpr int B_ = 8, C_ = 64, N_ = 4096, K_ = 32, O_ = 64;
typedef float v4 __attribute__((ext_vector_type(4)));

// ---------------- Kernel A: T'[b,n,o], U'[b,n,o] precompute ----------------
__global__ __launch_bounds__(256) void gat_pre(
    const float* __restrict__ x, const float* __restrict__ W,
    const float* __restrict__ gamma, const float* __restrict__ beta,
    const float* __restrict__ bn_mean, const float* __restrict__ bn_var,
    float* __restrict__ T, float* __restrict__ U)
{
    __shared__ float xsT[64][68];   // [c][n_local]
    __shared__ float wt1[64][68];   // [c][o] = W1[o][c]
    __shared__ float wtd[64][68];   // [c][o] = W2[o][c]-W1[o][c]

    const int blk = blockIdx.x;
    const int b = blk & 7;                 // XCD-pinned batch
    const int n_base = (blk >> 3) << 6;
    const int t = threadIdx.x;

    const float* xb = x + ((size_t)b * N_ + n_base) * C_;
    #pragma unroll
    for (int r = 0; r < 4; ++r) {
        const int e0 = r * 1024 + t * 4;
        // single-use, fully consumed by this one instruction -> NT is safe here
        const v4 v = __builtin_nontemporal_load(reinterpret_cast<const v4*>(xb + e0));
        xsT[(e0 + 0) & 63][(e0 + 0) >> 6] = v.x;
        xsT[(e0 + 1) & 63][(e0 + 1) >> 6] = v.y;
        xsT[(e0 + 2) & 63][(e0 + 2) >> 6] = v.z;
        xsT[(e0 + 3) & 63][(e0 + 3) >> 6] = v.w;
    }
    #pragma unroll
    for (int i = 0; i < 16; ++i) {
        const int idx = i * 256 + t;
        const int o = idx >> 6, c = idx & 63;
        const float w1 = W[o * 128 + c];
        const float w2 = W[o * 128 + 64 + c];
        wt1[c][o] = w1;
        wtd[c][o] = w2 - w1;
    }
    __syncthreads();

    const int o0 = (t & 15) * 4;
    const int n0 = (t >> 4) * 4;
    float accT[4][4] = {};
    float accU[4][4] = {};
    #pragma unroll 4
    for (int c = 0; c < 64; ++c) {
        const v4 xn = *reinterpret_cast<const v4*>(&xsT[c][n0]);
        const v4 w1 = *reinterpret_cast<const v4*>(&wt1[c][o0]);
        const v4 wd = *reinterpret_cast<const v4*>(&wtd[c][o0]);
        const float xa[4] = {xn.x, xn.y, xn.z, xn.w};
        const float wa[4] = {w1.x, w1.y, w1.z, w1.w};
        const float da[4] = {wd.x, wd.y, wd.z, wd.w};
        #pragma unroll
        for (int i = 0; i < 4; ++i)
            #pragma unroll
            for (int j = 0; j < 4; ++j) {
                accT[i][j] = fmaf(xa[i], wa[j], accT[i][j]);
                accU[i][j] = fmaf(xa[i], da[j], accU[i][j]);
            }
    }

    float inv[4], bias[4];
    #pragma unroll
    for (int j = 0; j < 4; ++j) {
        const int o = o0 + j;
        const float iv = gamma[o] * rsqrtf(bn_var[o] + 1e-5f);
        inv[j] = iv;
        bias[j] = beta[o] - bn_mean[o] * iv;
    }
    #pragma unroll
    for (int i = 0; i < 4; ++i) {
        const int n = n_base + n0 + i;
        float tvv[4], uvv[4];
        #pragma unroll
        for (int j = 0; j < 4; ++j) {
            tvv[j] = fmaf(accT[i][j], inv[j], bias[j]);
            uvv[j] = accU[i][j] * inv[j];
        }
        // normal (cached) stores: T/U are consumed by gat_main on the same XCD
        float* tp = T + ((size_t)b * N_ + n) * O_ + o0;
        float* up = U + ((size_t)b * N_ + n) * O_ + o0;
        *reinterpret_cast<v4*>(tp) = (v4){tvv[0], tvv[1], tvv[2], tvv[3]};
        *reinterpret_cast<v4*>(up) = (v4){uvv[0], uvv[1], uvv[2], uvv[3]};
    }
}

// ---------------- Kernel B: gather + softmax + weighted feature sum ----------------
__global__ __launch_bounds__(256) void gat_main(
    const int* __restrict__ gi, const float* __restrict__ feat,
    const float* __restrict__ T, const float* __restrict__ U,
    float* __restrict__ out)
{
    __shared__ float tmp[64][17];
    const int blk = blockIdx.x;
    const int b = blk & 7;                 // XCD-pinned batch
    const int n_base = (blk >> 3) * 16;
    const int t = threadIdx.x;
    const int w = t >> 6;
    const int lane = t & 63;               // = o

    const float* Ub = U + (size_t)b * N_ * O_ + lane;   // L2-resident gathers

    #pragma unroll 1
    for (int r = 0; r < 4; ++r) {
        const int n = n_base + w * 4 + r;
        int vi = 0;
        if (lane < 32) vi = __builtin_nontemporal_load(&gi[((size_t)b * N_ + n) * K_ + lane]);
        const float tv = __builtin_nontemporal_load(&T[((size_t)b * N_ + n) * O_ + lane]);

        // ---- issue ALL independent loads first: 8 feat dwordx4 + 32 gathers ----
        const v4* fp = reinterpret_cast<const v4*>(feat + (((size_t)b * O_ + lane) * N_ + n) * K_);
        v4 f[8];
        #pragma unroll
        for (int k4 = 0; k4 < 8; ++k4) f[k4] = fp[k4];      // cached (line reused 8x)

        float u[32];
        #pragma unroll
        for (int k = 0; k < 32; ++k) {
            const int m = __shfl(vi, k, 64);                // readlane -> SGPR base
            u[k] = Ub[(size_t)m * O_];                      // cached: keep U in L2
        }

        // ---- consume: leaky relu + online max ----
        float emax = -3.0e38f;
        #pragma unroll
        for (int k = 0; k < 32; ++k) {
            float ev = tv + u[k];
            ev = fmaxf(ev, 0.2f * ev);     // leaky relu, slope 0.2
            u[k] = ev;
            emax = fmaxf(emax, ev);
        }

        float num = 0.f, den = 0.f;
        #pragma unroll
        for (int k4 = 0; k4 < 8; ++k4) {
            const float p0 = __expf(u[k4 * 4 + 0] - emax);
            const float p1 = __expf(u[k4 * 4 + 1] - emax);
            const float p2 = __expf(u[k4 * 4 + 2] - emax);
            const float p3 = __expf(u[k4 * 4 + 3] - emax);
            num = fmaf(p0, f[k4].x, num); den += p0;
            num = fmaf(p1, f[k4].y, num); den += p1;
            num = fmaf(p2, f[k4].z, num); den += p2;
            num = fmaf(p3, f[k4].w, num); den += p3;
        }
        tmp[lane][w * 4 + r] = num / den;
    }
    __syncthreads();

    // coalesced transpose-write: 16 consecutive n per o = one 64B line
    #pragma unroll
    for (int r = 0; r < 4; ++r) {
        const int o = r * 16 + (t >> 4);
        const int ns = t & 15;
        __builtin_nontemporal_store(tmp[o][ns],
            &out[((size_t)b * O_ + o) * N_ + n_base + ns]);
    }
}

extern "C" void kernel_launch(void* const* d_in, const int* in_sizes, int n_in,
                              void* d_out, int out_size, void* d_ws, size_t ws_size,
                              hipStream_t stream) {
    const int*   gi      = (const int*)d_in[0];
    const float* x       = (const float*)d_in[1];
    const float* feat    = (const float*)d_in[2];
    const float* W       = (const float*)d_in[3];
    const float* gamma   = (const float*)d_in[4];
    const float* beta    = (const float*)d_in[5];
    const float* bn_mean = (const float*)d_in[6];
    const float* bn_var  = (const float*)d_in[7];
    float* out = (float*)d_out;

    float* T = (float*)d_ws;                          // B*N*O floats = 8MB
    float* U = T + (size_t)B_ * N_ * O_;              // + 8MB

    gat_pre<<<dim3(B_ * (N_ / 64)), dim3(256), 0, stream>>>(
        x, W, gamma, beta, bn_mean, bn_var, T, U);
    gat_main<<<dim3(B_ * (N_ / 16)), dim3(256), 0, stream>>>(
        gi, feat, T, U, out);
}

// Round 11
// 378.844 us; speedup vs baseline: 1.3890x; 1.1232x over previous
//
#include <hip/hip_runtime.h>

// GraphAttention: e[b,n,k,o] = T[b,n,o] + U[b,idx[b,n,k],o]  (exact factorization
// of einsum('bnkc,oc', [centre-nb, nb], W)); BN affine folded into T,U.
// Then leaky(0.2) -> softmax over k -> dot with feature[b,o,n,:] -> out[b,o,n].
//
// R11: cross-round algebra shows gat_main ~112us in R0 AND R10 (batching did
// nothing) at only ~40% effective HBM BW. Theory: lane=o makes every feat
// wave-load 64 scattered 16B requests (512KB lane stride) -> DRAM efficiency
// collapse. Fix: cooperatively stage feat [4n][64o][32k] (32KB) into LDS with
// fully-contiguous 512B-per-chunk global reads, XOR-swizzled LDS layout
// (kk ^ 2*(o&15), v2-granular) so scatter-write AND per-o read run at the
// LDS floor. U-gathers issue first; latency hides under staging+barrier.

constexpr int B_ = 8, C_ = 64, N_ = 4096, K_ = 32, O_ = 64;
typedef float v4 __attribute__((ext_vector_type(4)));
typedef float v2 __attribute__((ext_vector_type(2)));

// ---------------- Kernel A: T'[b,n,o], U'[b,n,o] precompute ----------------
__global__ __launch_bounds__(256) void gat_pre(
    const float* __restrict__ x, const float* __restrict__ W,
    const float* __restrict__ gamma, const float* __restrict__ beta,
    const float* __restrict__ bn_mean, const float* __restrict__ bn_var,
    float* __restrict__ T, float* __restrict__ U)
{
    __shared__ float xsT[64][68];   // [c][n_local]
    __shared__ float wt1[64][68];   // [c][o] = W1[o][c]
    __shared__ float wtd[64][68];   // [c][o] = W2[o][c]-W1[o][c]

    const int blk = blockIdx.x;
    const int b = blk & 7;                 // XCD-pinned batch
    const int n_base = (blk >> 3) << 6;
    const int t = threadIdx.x;

    const float* xb = x + ((size_t)b * N_ + n_base) * C_;
    #pragma unroll
    for (int r = 0; r < 4; ++r) {
        const int e0 = r * 1024 + t * 4;
        // single-use, fully consumed by this one instruction -> NT safe
        const v4 v = __builtin_nontemporal_load(reinterpret_cast<const v4*>(xb + e0));
        xsT[(e0 + 0) & 63][(e0 + 0) >> 6] = v.x;
        xsT[(e0 + 1) & 63][(e0 + 1) >> 6] = v.y;
        xsT[(e0 + 2) & 63][(e0 + 2) >> 6] = v.z;
        xsT[(e0 + 3) & 63][(e0 + 3) >> 6] = v.w;
    }
    #pragma unroll
    for (int i = 0; i < 16; ++i) {
        const int idx = i * 256 + t;
        const int o = idx >> 6, c = idx & 63;
        const float w1 = W[o * 128 + c];
        const float w2 = W[o * 128 + 64 + c];
        wt1[c][o] = w1;
        wtd[c][o] = w2 - w1;
    }
    __syncthreads();

    const int o0 = (t & 15) * 4;
    const int n0 = (t >> 4) * 4;
    float accT[4][4] = {};
    float accU[4][4] = {};
    #pragma unroll 4
    for (int c = 0; c < 64; ++c) {
        const v4 xn = *reinterpret_cast<const v4*>(&xsT[c][n0]);
        const v4 w1 = *reinterpret_cast<const v4*>(&wt1[c][o0]);
        const v4 wd = *reinterpret_cast<const v4*>(&wtd[c][o0]);
        const float xa[4] = {xn.x, xn.y, xn.z, xn.w};
        const float wa[4] = {w1.x, w1.y, w1.z, w1.w};
        const float da[4] = {wd.x, wd.y, wd.z, wd.w};
        #pragma unroll
        for (int i = 0; i < 4; ++i)
            #pragma unroll
            for (int j = 0; j < 4; ++j) {
                accT[i][j] = fmaf(xa[i], wa[j], accT[i][j]);
                accU[i][j] = fmaf(xa[i], da[j], accU[i][j]);
            }
    }

    float inv[4], bias[4];
    #pragma unroll
    for (int j = 0; j < 4; ++j) {
        const int o = o0 + j;
        const float iv = gamma[o] * rsqrtf(bn_var[o] + 1e-5f);
        inv[j] = iv;
        bias[j] = beta[o] - bn_mean[o] * iv;
    }
    #pragma unroll
    for (int i = 0; i < 4; ++i) {
        const int n = n_base + n0 + i;
        float tvv[4], uvv[4];
        #pragma unroll
        for (int j = 0; j < 4; ++j) {
            tvv[j] = fmaf(accT[i][j], inv[j], bias[j]);
            uvv[j] = accU[i][j] * inv[j];
        }
        float* tp = T + ((size_t)b * N_ + n) * O_ + o0;
        float* up = U + ((size_t)b * N_ + n) * O_ + o0;
        *reinterpret_cast<v4*>(tp) = (v4){tvv[0], tvv[1], tvv[2], tvv[3]};
        *reinterpret_cast<v4*>(up) = (v4){uvv[0], uvv[1], uvv[2], uvv[3]};
    }
}

// ---------------- Kernel B: gather + softmax + LDS-staged feature sum ----------------
// block = 256 (4 waves), 16 n per block in 4 stages of 4 n. Per stage:
// issue 32 U-gathers (wave's own row) -> stage feat tile to LDS (contiguous
// 512B chunks) -> barrier -> leaky/max/exp + LDS feat reads.
__global__ __launch_bounds__(256) void gat_main(
    const int* __restrict__ gi, const float* __restrict__ feat,
    const float* __restrict__ T, const float* __restrict__ U,
    float* __restrict__ out)
{
    __shared__ float fs[4 * 2048];  // [n'][o][32k] dwords, col XOR-swizzled
    __shared__ float tmp[64][17];

    const int blk = blockIdx.x;
    const int b = blk & 7;                 // XCD-pinned batch
    const int n_base = (blk >> 3) * 16;
    const int t = threadIdx.x;
    const int w = t >> 6;
    const int lane = t & 63;               // = o in compute/gather phases

    const float* Ub = U + (size_t)b * N_ * O_ + lane;   // L2-resident gathers

    // prefetch per-stage row metadata (stage s row = n_base + s*4 + w)
    int   vi[4];
    float tv[4];
    #pragma unroll
    for (int s = 0; s < 4; ++s) {
        const int n = n_base + s * 4 + w;
        vi[s] = (lane < 32)
            ? __builtin_nontemporal_load(&gi[((size_t)b * N_ + n) * K_ + lane]) : 0;
        tv[s] = __builtin_nontemporal_load(&T[((size_t)b * N_ + n) * O_ + lane]);
    }

    // staging geometry: thread t, iter i -> f4 = t + 256*i covers chunk
    // o = f4>>5 (512B contiguous), v4-within-chunk j = f4&31.
    const int swz = 2 * (lane & 15);       // read-side swizzle for this lane's o

    #pragma unroll 1
    for (int s = 0; s < 4; ++s) {
        // ---- issue this wave's 32 U gathers first (consumed after barrier) ----
        float u[32];
        #pragma unroll
        for (int k = 0; k < 32; ++k) {
            const int m = __shfl(vi[s], k, 64);
            u[k] = Ub[(size_t)m * O_];              // cached: keep U in L2
        }

        // ---- cooperative feat staging: [4n][64o][32k] = 32KB, contiguous ----
        const float* fbase = feat + ((size_t)b * O_ * N_ + (size_t)(n_base + s * 4)) * K_;
        v4 g[8];
        #pragma unroll
        for (int i = 0; i < 8; ++i) {
            const int f4 = t + 256 * i;
            const int o = f4 >> 5, j = f4 & 31;
            // full 64B line consumed by one instruction -> NT safe (stream)
            g[i] = __builtin_nontemporal_load(
                reinterpret_cast<const v4*>(fbase + (size_t)o * (N_ * K_) + j * 4));
        }

        __syncthreads();        // all waves finished reading previous tile
        #pragma unroll
        for (int i = 0; i < 8; ++i) {
            const int f4 = t + 256 * i;
            const int o = f4 >> 5, j = f4 & 31;
            const int nr = j >> 3, kk = (j * 4) & 31;
            const int sw = 2 * (o & 15);
            const int base = nr * 2048 + o * 32;
            // v2-granular swizzled scatter (conflict-free at LDS floor)
            *reinterpret_cast<v2*>(&fs[base + ((kk + 0) ^ sw)]) = (v2){g[i].x, g[i].y};
            *reinterpret_cast<v2*>(&fs[base + ((kk + 2) ^ sw)]) = (v2){g[i].z, g[i].w};
        }
        __syncthreads();        // tile visible

        // ---- leaky relu + online max ----
        float emax = -3.0e38f;
        #pragma unroll
        for (int k = 0; k < 32; ++k) {
            float ev = tv[s] + u[k];
            ev = fmaxf(ev, 0.2f * ev);              // leaky relu, slope 0.2
            u[k] = ev;
            emax = fmaxf(emax, ev);
        }

        // ---- softmax-weighted feature sum; feat from LDS (row n' = w) ----
        const int rbase = w * 2048 + lane * 32;
        float num = 0.f, den = 0.f;
        #pragma unroll
        for (int k2 = 0; k2 < 16; ++k2) {
            const v2 f = *reinterpret_cast<const v2*>(&fs[rbase + ((2 * k2) ^ swz)]);
            const float p0 = __expf(u[k2 * 2 + 0] - emax);
            const float p1 = __expf(u[k2 * 2 + 1] - emax);
            num = fmaf(p0, f.x, num); den += p0;
            num = fmaf(p1, f.y, num); den += p1;
        }
        tmp[lane][s * 4 + w] = num / den;
    }
    __syncthreads();

    // coalesced transpose-write: 16 consecutive n per o = one 64B line
    #pragma unroll
    for (int r = 0; r < 4; ++r) {
        const int o = r * 16 + (t >> 4);
        const int ns = t & 15;
        __builtin_nontemporal_store(tmp[o][ns],
            &out[((size_t)b * O_ + o) * N_ + n_base + ns]);
    }
}

extern "C" void kernel_launch(void* const* d_in, const int* in_sizes, int n_in,
                              void* d_out, int out_size, void* d_ws, size_t ws_size,
                              hipStream_t stream) {
    const int*   gi      = (const int*)d_in[0];
    const float* x       = (const float*)d_in[1];
    const float* feat    = (const float*)d_in[2];
    const float* W       = (const float*)d_in[3];
    const float* gamma   = (const float*)d_in[4];
    const float* beta    = (const float*)d_in[5];
    const float* bn_mean = (const float*)d_in[6];
    const float* bn_var  = (const float*)d_in[7];
    float* out = (float*)d_out;

    float* T = (float*)d_ws;                          // B*N*O floats = 8MB
    float* U = T + (size_t)B_ * N_ * O_;              // + 8MB

    gat_pre<<<dim3(B_ * (N_ / 64)), dim3(256), 0, stream>>>(
        x, W, gamma, beta, bn_mean, bn_var, T, U);
    gat_main<<<dim3(B_ * (N_ / 16)), dim3(256), 0, stream>>>(
        gi, feat, T, U, out);
}